// Round 13
// baseline (152.559 us; speedup 1.0000x reference)
//
#include <hip/hip_runtime.h>
#include <hip/hip_bf16.h>
#include <stdint.h>

// Problem constants
#define NT 4096      // tokens
#define DM 320       // model dim
#define NH 8         // heads
#define DH 40        // head dim
#define KS 4         // split-K factor over the key dimension
#define QSCALE 0.22811013f  // (1/sqrt(40)) * log2(e): folded into Q so p = exp2(qk)
#define PSTR 68      // P-tile LDS row stride (ushorts): b64 8B-aligned, <=2-way banks
#define KFJB 640     // Kf shorts per 16-key block: 512 (k<32) + 128 (k=32..39, quad0)
#define WSTR 330     // W-slab LDS row stride (ushorts): 165 dw, gcd(165,32)=1

typedef float f32x4 __attribute__((ext_vector_type(4)));
typedef __bf16 bf16x8 __attribute__((ext_vector_type(8)));

__device__ __forceinline__ unsigned short f2b(float f) {
  unsigned u = __builtin_bit_cast(unsigned, f);
  u += 0x7FFFu + ((u >> 16) & 1u);   // RNE
  return (unsigned short)(u >> 16);
}

__device__ __forceinline__ bf16x8 ld_bf8(const unsigned short* p) {
  uint4 v = *(const uint4*)p;        // 16B load
  return __builtin_bit_cast(bf16x8, v);
}

__device__ __forceinline__ f32x4 mfma16(bf16x8 a, bf16x8 b, f32x4 c) {
  return __builtin_amdgcn_mfma_f32_16x16x32_bf16(a, b, c, 0, 0, 0);
}

__device__ __forceinline__ float fexp2(float x) {
#if __has_builtin(__builtin_amdgcn_exp2f)
  return __builtin_amdgcn_exp2f(x);
#else
  float r; asm("v_exp_f32 %0, %1" : "=v"(r) : "v"(x)); return r;
#endif
}

__device__ __forceinline__ uint2 pack4(float a, float b, float c, float d) {
  uint2 pk;
  pk.x = (unsigned)f2b(a) | ((unsigned)f2b(b) << 16);
  pk.y = (unsigned)f2b(c) | ((unsigned)f2b(d) << 16);
  return pk;
}

// Fragment-major index: element (outer o in 16-tile `tile`, inner k of nk 32-tiles)
__device__ __forceinline__ size_t fmi(int tile, int nk, int k, int o) {
  return ((size_t)tile * nk + (k >> 5)) * 512 + (size_t)((k >> 3) & 3) * 128 +
         (size_t)(o & 15) * 8 + (k & 7);
}

// ---------------- kernel 1: fused prep + QKV projection ----------------
// grid (64, 16): cy 0..14 = GEMM tiles (a = cy/5: Q/K/V; cc0 = cy%5*64);
// cy 15, bx<16 = signatures. Per GEMM block: stage own 64c x 320k W-slab fp32->
// bf16 in LDS (one barrier), A-frags from fp32 x inline. Replaces prep_kernel.
// Q/K: D[c][m] via mfma(W,x) -> uint2 stores. V: D[m][c] via mfma(x,W).
__global__ __launch_bounds__(256, 3) void qkv_gemm(
    const float* __restrict__ x, const float* __restrict__ g,
    const float* __restrict__ Wq, const float* __restrict__ Wk,
    const float* __restrict__ Wv,
    unsigned char* __restrict__ sigb, unsigned short* __restrict__ Qf,
    unsigned short* __restrict__ Kf, unsigned short* __restrict__ Vf) {
  __shared__ __align__(16) unsigned short wt[64 * WSTR];   // W^T [c][k] 42240 B
  const int t = threadIdx.x;
  const int cy = blockIdx.y;
  if (cy == 15) {                             // ---- phase signatures
    if (blockIdx.x < 16) {
      int i = blockIdx.x * 256 + t;
      unsigned s = 0;
      if (g[i] != 0.f)          s |= 1u;
      if (g[NT + i] != 0.f)     s |= 2u;
      if (g[2 * NT + i] != 0.f) s |= 4u;
      sigb[i] = (unsigned char)s;
    }
    return;
  }
  const int w = t >> 6, lane = t & 63, quad = lane >> 4, ln = lane & 15;
  const int m0 = blockIdx.x * 64;
  const int a = cy / 5;                       // 0=Q 1=K 2=V
  const int cc0 = (cy % 5) * 64;
  const float* Wsrc = (a == 0) ? Wq : ((a == 1) ? Wk : Wv);

  // stage W^T slab: read 320k x 64c fp32 coalesced, write LDS [c][k] bf16
#pragma unroll
  for (int i = 0; i < 20; ++i) {
    int k = (t >> 4) + i * 16;
    int c4 = (t & 15) * 4;
    float4 w4 = *(const float4*)&Wsrc[(size_t)k * DM + cc0 + c4];
    wt[(c4 + 0) * WSTR + k] = f2b(w4.x);
    wt[(c4 + 1) * WSTR + k] = f2b(w4.y);
    wt[(c4 + 2) * WSTR + k] = f2b(w4.z);
    wt[(c4 + 3) * WSTR + k] = f2b(w4.w);
  }
  __syncthreads();

  const float* Arow = x + (size_t)(m0 + w * 16 + ln) * DM + quad * 8;
  f32x4 acc[4] = {{0,0,0,0},{0,0,0,0},{0,0,0,0},{0,0,0,0}};
  for (int kc = 0; kc < 10; ++kc) {
    float4 a0 = *(const float4*)(Arow + kc * 32);
    float4 a1 = *(const float4*)(Arow + kc * 32 + 4);
    unsigned short af8[8];
    af8[0] = f2b(a0.x); af8[1] = f2b(a0.y); af8[2] = f2b(a0.z); af8[3] = f2b(a0.w);
    af8[4] = f2b(a1.x); af8[5] = f2b(a1.y); af8[6] = f2b(a1.z); af8[7] = f2b(a1.w);
    bf16x8 xf = ld_bf8(af8);
#pragma unroll
    for (int nt = 0; nt < 4; ++nt) {
      bf16x8 wf = ld_bf8(&wt[(nt * 16 + ln) * WSTR + kc * 32 + quad * 8]);
      if (a < 2) acc[nt] = mfma16(wf, xf, acc[nt]);   // D[c=quad*4+r][m=ln]
      else       acc[nt] = mfma16(xf, wf, acc[nt]);   // D[m=quad*4+r][c=ln]
    }
  }
  if (a == 0) {
    const int m = m0 + w * 16 + ln;
#pragma unroll
    for (int nt = 0; nt < 4; ++nt) {
      int c = cc0 + nt * 16 + quad * 4;       // r=0 base; no h/8-boundary crossing
      int h = c / DH, d = c % DH;
      uint2 pk = pack4(acc[nt][0] * QSCALE, acc[nt][1] * QSCALE,
                       acc[nt][2] * QSCALE, acc[nt][3] * QSCALE);
      *(uint2*)&Qf[fmi(h * 256 + (m >> 4), 2, d, m)] = pk;
    }
  } else if (a == 1) {
    const int m = m0 + w * 16 + ln;
#pragma unroll
    for (int nt = 0; nt < 4; ++nt) {
      int c = cc0 + nt * 16 + quad * 4;
      int h = c / DH, d = c % DH;
      uint2 pk = pack4(acc[nt][0], acc[nt][1], acc[nt][2], acc[nt][3]);
      size_t base = ((size_t)h * 256 + (m >> 4)) * KFJB;
      size_t idx = (d < 32)
          ? base + (size_t)(d >> 3) * 128 + (size_t)(m & 15) * 8 + (d & 7)
          : base + 512 + (size_t)(m & 15) * 8 + (d - 32);
      *(uint2*)&Kf[idx] = pk;
    }
  } else {
    const int mb = m0 + w * 16 + quad * 4;    // r=0 base (4 consecutive m)
#pragma unroll
    for (int nt = 0; nt < 4; ++nt) {
      int c = cc0 + nt * 16 + ln;
      int h = c / DH, d = c % DH;
      uint2 pk = pack4(acc[nt][0], acc[nt][1], acc[nt][2], acc[nt][3]);
      size_t idx = ((((((size_t)(h * 64 + (mb >> 6)) * 3 + (d >> 4)) * 2 +
                       ((mb >> 5) & 1)) * 4 + ((mb >> 3) & 3)) * 16 + (d & 15))) * 8 +
                   (mb & 7);
      *(uint2*)&Vf[idx] = pk;
    }
  }
}

// ---------------- kernel 2: barrier-free masked attention ----------------
// grid (32 q-tiles of 128 rows, 8 heads, KS=4); block 256 = 4 waves x 32 q-rows.
__global__ __launch_bounds__(256, 4) void attn_kernel(
    const unsigned short* __restrict__ Qf, const unsigned short* __restrict__ Kf,
    const unsigned short* __restrict__ Vf, const unsigned char* __restrict__ sigb,
    unsigned short* __restrict__ Opf, float* __restrict__ Lpart) {
  __shared__ __align__(16) unsigned short pt[4][32 * PSTR];   // per-wave P^T 17408 B
  const int t = threadIdx.x;
  const int w = t >> 6, lane = t & 63, quad = lane >> 4, ln = lane & 15;
  const int h = blockIdx.y, qt = blockIdx.x, sp = blockIdx.z;
  const int qrow = qt * 128 + w * 32;
  const int j0 = sp * 16;

  const unsigned short* Kfh = Kf + (size_t)h * 256 * KFJB;
  const unsigned short* Vfh = Vf + (size_t)h * 196608;   // 64jt * 3ot * 2c * 512
  unsigned short* ptw = pt[w];
  const uint4 z4 = {0, 0, 0, 0};
  const uint4 ones4 = {0x3F803F80u, 0x3F803F80u, 0x3F803F80u, 0x3F803F80u};
  const bool vone = (ln == 8);             // d=40 rows of the ot=2 V-frag -> 1.0

  bf16x8 qa[2][2];
  unsigned sqx4[2], uqx4[2];
  f32x4 o[3][2] = {{{0,0,0,0},{0,0,0,0}},{{0,0,0,0},{0,0,0,0}},{{0,0,0,0},{0,0,0,0}}};

#pragma unroll
  for (int tq = 0; tq < 2; ++tq) {
    int row = qrow + tq * 16 + ln;
    size_t qbase = ((size_t)(h * 256 + qt * 8 + w * 2 + tq) * 2) * 512;
    qa[tq][0] = ld_bf8(Qf + qbase + lane * 8);          // k 0..31, contiguous 1KB
    uint4 q1 = z4;                                      // k 32..63: quad0 real
    if (quad == 0) q1 = *(const uint4*)(Qf + qbase + 512 + lane * 8);
    qa[tq][1] = __builtin_bit_cast(bf16x8, q1);
    unsigned s = sigb[row];
    sqx4[tq] = s * 0x01010101u;
    uqx4[tq] = (s == 0u) ? 0xFFFFFFFFu : 0u;
    if (s == 0u) {                 // uniform row: logits exactly 0 -> p = 1
      qa[tq][0] = __builtin_bit_cast(bf16x8, z4);
      qa[tq][1] = __builtin_bit_cast(bf16x8, z4);
    }
  }

  for (int jt = j0; jt < j0 + 16; ++jt) {
    // K fragments from compact Kf: 4 x 1KB + 4 x 256B (quad0) coalesced loads
    uint4 kfr0[4], kfr1[4];
#pragma unroll
    for (int nt = 0; nt < 4; ++nt) {
      const unsigned short* kb = Kfh + (size_t)(jt * 4 + nt) * KFJB;
      kfr0[nt] = *(const uint4*)(kb + lane * 8);
      kfr1[nt] = z4;
      if (lane < 16) kfr1[nt] = *(const uint4*)(kb + 512 + lane * 8);
    }

#pragma unroll
    for (int nt = 0; nt < 4; ++nt) {
      bf16x8 ka0 = __builtin_bit_cast(bf16x8, kfr0[nt]);
      bf16x8 ka1 = __builtin_bit_cast(bf16x8, kfr1[nt]);
      unsigned spj = *(const unsigned*)(sigb + jt * 64 + nt * 16 + quad * 4);
#pragma unroll
      for (int tq = 0; tq < 2; ++tq) {
        f32x4 acc = {0.f, 0.f, 0.f, 0.f};
        acc = mfma16(ka0, qa[tq][0], acc);    // S^T[j=nt*16+quad*4+r][m=ln]
        acc = mfma16(ka1, qa[tq][1], acc);
        unsigned m4 = (spj & sqx4[tq]) | uqx4[tq];   // byte r != 0 <=> unmasked
        unsigned u[4];
#pragma unroll
        for (int r = 0; r < 4; ++r) {
          unsigned mb = (m4 >> (8 * r)) & 255u;      // v_bfe
          float am = mb ? acc[r] : -3.0e38f;         // masked -> exp2 = 0
          u[r] = __builtin_bit_cast(unsigned, fexp2(am));
        }
        uint2 pk;                                    // truncate-to-bf16 pack
        pk.x = (u[0] >> 16) | (u[1] & 0xffff0000u);  // (j+0, j+1)
        pk.y = (u[2] >> 16) | (u[3] & 0xffff0000u);  // (j+2, j+3)
        *(uint2*)&ptw[(tq * 16 + ln) * PSTR + nt * 16 + quad * 4] = pk;  // b64
      }
    }
    // V fragments (6 coalesced 1KB wave loads); ones-column d=40 in-register
    uint4 vfr[6];
#pragma unroll
    for (int ot = 0; ot < 3; ++ot)
#pragma unroll
      for (int c = 0; c < 2; ++c)
        vfr[ot * 2 + c] =
            *(const uint4*)(Vfh + ((size_t)((jt * 3 + ot) * 2 + c)) * 512 + lane * 8);
    if (vone) { vfr[4] = ones4; vfr[5] = ones4; }

    asm volatile("s_waitcnt lgkmcnt(0)" ::: "memory");   // wave-private P RAW
    bf16x8 pb[2][2];
#pragma unroll
    for (int tq = 0; tq < 2; ++tq) {
      pb[tq][0] = ld_bf8(&ptw[(tq * 16 + ln) * PSTR + quad * 8]);
      pb[tq][1] = ld_bf8(&ptw[(tq * 16 + ln) * PSTR + 32 + quad * 8]);
    }
#pragma unroll
    for (int ot = 0; ot < 3; ++ot) {
      bf16x8 va0 = __builtin_bit_cast(bf16x8, vfr[ot * 2]);
      bf16x8 va1 = __builtin_bit_cast(bf16x8, vfr[ot * 2 + 1]);
#pragma unroll
      for (int tq = 0; tq < 2; ++tq) {
        o[ot][tq] = mfma16(va0, pb[tq][0], o[ot][tq]);   // O^T[d][m]
        o[ot][tq] = mfma16(va1, pb[tq][1], o[ot][tq]);
      }
    }
  }

  // epilogue: O^T d = ot*16+quad*4+r; write frag-major Opf; d=40 -> denominator
#pragma unroll
  for (int tq = 0; tq < 2; ++tq) {
    int m = qrow + tq * 16 + ln;
#pragma unroll
    for (int ot = 0; ot < 3; ++ot) {
      int d0 = ot * 16 + quad * 4;
      if (d0 < DH) {
        int c = h * DH + d0;                  // 4 consecutive c, no 8-crossing
        uint2 pk = pack4(o[ot][tq][0], o[ot][tq][1], o[ot][tq][2], o[ot][tq][3]);
        *(uint2*)&Opf[fmi(sp * 256 + (m >> 4), 10, c, m)] = pk;
      }
    }
    if (quad == 2)
      Lpart[sp * NT + m] = o[2][tq][0];       // MFMA-computed denominator
  }
}

// ---------------- kernel 3: out projection + split-K combine + bias ----------------
__global__ __launch_bounds__(256, 4) void out_gemm(
    const unsigned short* __restrict__ Opf, const float* __restrict__ Lpart,
    const float* __restrict__ Wo, const float* __restrict__ bo,
    float* __restrict__ out) {
  __shared__ __align__(16) unsigned short wt[64 * WSTR];   // Wo^T [c][k] 42240 B
  const int t = threadIdx.x;
  const int w = t >> 6, lane = t & 63, quad = lane >> 4, ln = lane & 15;
  const int m0 = blockIdx.x * 64;
  const int cc0 = blockIdx.y * 64;
  const int mt = (m0 >> 4) + w;
  const int m = m0 + w * 16 + ln;

  // stage Wo^T slab (same pattern as qkv)
#pragma unroll
  for (int i = 0; i < 20; ++i) {
    int k = (t >> 4) + i * 16;
    int c4 = (t & 15) * 4;
    float4 w4 = *(const float4*)&Wo[(size_t)k * DM + cc0 + c4];
    wt[(c4 + 0) * WSTR + k] = f2b(w4.x);
    wt[(c4 + 1) * WSTR + k] = f2b(w4.y);
    wt[(c4 + 2) * WSTR + k] = f2b(w4.z);
    wt[(c4 + 3) * WSTR + k] = f2b(w4.w);
  }
  float ls = 0.f;
#pragma unroll
  for (int sp = 0; sp < KS; ++sp) ls += Lpart[sp * NT + m];
  const float inv = 1.f / ls;
  __syncthreads();

  f32x4 acc[4] = {{0,0,0,0},{0,0,0,0},{0,0,0,0},{0,0,0,0}};
  for (int kc = 0; kc < 10; ++kc) {
    float s8[8] = {0, 0, 0, 0, 0, 0, 0, 0};
#pragma unroll
    for (int sp = 0; sp < KS; ++sp) {
      uint4 v = *(const uint4*)(Opf + ((size_t)((sp * 256 + mt) * 10 + kc)) * 512 +
                                lane * 8);
      unsigned vv[4] = {v.x, v.y, v.z, v.w};
#pragma unroll
      for (int j = 0; j < 4; ++j) {
        s8[2 * j]     += __builtin_bit_cast(float, vv[j] << 16);
        s8[2 * j + 1] += __builtin_bit_cast(float, vv[j] & 0xffff0000u);
      }
    }
    unsigned short af8[8];
#pragma unroll
    for (int j = 0; j < 8; ++j) af8[j] = f2b(s8[j] * inv);
    bf16x8 af = ld_bf8(af8);
#pragma unroll
    for (int nt = 0; nt < 4; ++nt) {
      bf16x8 wf = ld_bf8(&wt[(nt * 16 + ln) * WSTR + kc * 32 + quad * 8]);
      acc[nt] = mfma16(wf, af, acc[nt]);      // D[c=quad*4+r][m=ln]
    }
  }
#pragma unroll
  for (int nt = 0; nt < 4; ++nt) {
    int c = cc0 + nt * 16 + quad * 4;
    float4 bv = *(const float4*)(bo + c);
    float4 ov;
    ov.x = acc[nt][0] + bv.x;
    ov.y = acc[nt][1] + bv.y;
    ov.z = acc[nt][2] + bv.z;
    ov.w = acc[nt][3] + bv.w;
    *(float4*)(out + (size_t)m * DM + c) = ov;
  }
}

// ---------------- launcher ----------------
extern "C" void kernel_launch(void* const* d_in, const int* in_sizes, int n_in,
                              void* d_out, int out_size, void* d_ws, size_t ws_size,
                              hipStream_t stream) {
  const float* x  = (const float*)d_in[0];
  const float* g  = (const float*)d_in[1];
  const float* Wq = (const float*)d_in[2];
  const float* Wk = (const float*)d_in[3];
  const float* Wv = (const float*)d_in[4];
  const float* Wo = (const float*)d_in[5];
  const float* bo = (const float*)d_in[6];
  float* out = (float*)d_out;

  char* ws = (char*)d_ws;
  const size_t SIG_OFF = 0;
  const size_t QF_OFF  = 16384;
  const size_t KF_OFF  = QF_OFF + (size_t)NH * 256 * 2 * 512 * 2;   // +4.19 MB
  const size_t VF_OFF  = KF_OFF + (size_t)NH * 256 * KFJB * 2;      // +2.62 MB
  const size_t OPF_OFF = VF_OFF + (size_t)NH * 196608 * 2;          // +3.15 MB
  const size_t LP_OFF  = OPF_OFF + (size_t)KS * 256 * 10 * 512 * 2; // +10.49 MB
  unsigned char* sigb  = (unsigned char*)(ws + SIG_OFF);
  unsigned short* Qf   = (unsigned short*)(ws + QF_OFF);
  unsigned short* Kf   = (unsigned short*)(ws + KF_OFF);
  unsigned short* Vf   = (unsigned short*)(ws + VF_OFF);
  unsigned short* Opf  = (unsigned short*)(ws + OPF_OFF);
  float* Lpart         = (float*)(ws + LP_OFF);

  // No memset: Qf half-1 quad>=1 garbage zeroed in-register; Vf d=40 ones
  // in-register; Vf d=41..47 garbage feeds only discarded lanes (no NaN).
  qkv_gemm<<<dim3(64, 16), 256, 0, stream>>>(x, g, Wq, Wk, Wv, sigb, Qf, Kf, Vf);
  attn_kernel<<<dim3(32, NH, KS), 256, 0, stream>>>(Qf, Kf, Vf, sigb, Opf, Lpart);
  out_gemm<<<dim3(64, 5), 256, 0, stream>>>(Opf, Lpart, Wo, bo, out);
}

// Round 14
// 146.785 us; speedup vs baseline: 1.0393x; 1.0393x over previous
//
#include <hip/hip_runtime.h>
#include <hip/hip_bf16.h>
#include <stdint.h>

// Problem constants
#define NT 4096      // tokens
#define DM 320       // model dim
#define NH 8         // heads
#define DH 40        // head dim
#define KS 4         // split-K factor over the key dimension
#define QSCALE 0.22811013f  // (1/sqrt(40)) * log2(e): folded into Q so p = exp2(qk)
#define PSTR 68      // P-tile LDS row stride (ushorts): b64 8B-aligned, <=2-way banks
#define KFJB 640     // Kf shorts per 16-key block: 512 (k<32) + 128 (k=32..39, quad0)

typedef float f32x4 __attribute__((ext_vector_type(4)));
typedef __bf16 bf16x8 __attribute__((ext_vector_type(8)));

__device__ __forceinline__ unsigned short f2b(float f) {
  unsigned u = __builtin_bit_cast(unsigned, f);
  u += 0x7FFFu + ((u >> 16) & 1u);   // RNE
  return (unsigned short)(u >> 16);
}

__device__ __forceinline__ bf16x8 ld_bf8(const unsigned short* p) {
  uint4 v = *(const uint4*)p;        // 16B load
  return __builtin_bit_cast(bf16x8, v);
}

__device__ __forceinline__ f32x4 mfma16(bf16x8 a, bf16x8 b, f32x4 c) {
  return __builtin_amdgcn_mfma_f32_16x16x32_bf16(a, b, c, 0, 0, 0);
}

__device__ __forceinline__ float fexp2(float x) {
#if __has_builtin(__builtin_amdgcn_exp2f)
  return __builtin_amdgcn_exp2f(x);
#else
  float r; asm("v_exp_f32 %0, %1" : "=v"(r) : "v"(x)); return r;
#endif
}

__device__ __forceinline__ uint2 pack4(float a, float b, float c, float d) {
  uint2 pk;
  pk.x = (unsigned)f2b(a) | ((unsigned)f2b(b) << 16);
  pk.y = (unsigned)f2b(c) | ((unsigned)f2b(d) << 16);
  return pk;
}

// Fragment-major index: element (outer o in 16-tile `tile`, inner k of nk 32-tiles)
__device__ __forceinline__ size_t fmi(int tile, int nk, int k, int o) {
  return ((size_t)tile * nk + (k >> 5)) * 512 + (size_t)((k >> 3) & 3) * 128 +
         (size_t)(o & 15) * 8 + (k & 7);
}

// ---------------- kernel 1: prep (weights->Wtf | sig | x->xbf) ----------------
// blocks 0..99: weights -> bf16 transposed frag-major; 100..115: signatures;
// 116..243: x -> bf16 frag-major (10 float4/thread, grid-strided).
__global__ __launch_bounds__(256) void prep_kernel(
    const float* __restrict__ x, const float* __restrict__ g,
    const float* __restrict__ Wq, const float* __restrict__ Wk,
    const float* __restrict__ Wv, const float* __restrict__ Wo,
    unsigned short* __restrict__ xbf, unsigned char* __restrict__ sigb,
    unsigned short* __restrict__ Wtf) {
  __shared__ __align__(16) unsigned short lt[64 * 72];
  const int b = blockIdx.x, t = threadIdx.x;
  if (b >= 116) {                       // ---- x -> bf16 frag-major (fat blocks)
    int base = (b - 116) * 2560;        // 128 blocks x 2560 float4
#pragma unroll
    for (int j = 0; j < 10; ++j) {
      int i = (base + j * 256 + t) * 4;
      int m = i / DM, k = i % DM;
      float4 v = *(const float4*)(x + i);
      ushort4 u;
      u.x = f2b(v.x); u.y = f2b(v.y); u.z = f2b(v.z); u.w = f2b(v.w);
      *(ushort4*)(xbf + fmi(m >> 4, 10, k, m)) = u;
    }
    return;
  }
  if (b >= 100) {                       // ---- phase signatures
    int i = (b - 100) * 256 + t;
    unsigned s = 0;
    if (g[i] != 0.f)          s |= 1u;
    if (g[NT + i] != 0.f)     s |= 2u;
    if (g[2 * NT + i] != 0.f) s |= 4u;
    sigb[i] = (unsigned char)s;
    return;
  }
  // ---- weights -> bf16 transposed frag-major
  int kx = b % 5, cy = b / 5;           // kx: k-tile, cy: c-tile over 4 mats
  int cm = cy % 5;
  const float* src;
  int rowbase;
  if (cy < 5)       { src = Wq; rowbase = cm * 64; }
  else if (cy < 10) { src = Wk; rowbase = 320 + cm * 64; }
  else if (cy < 15) { src = Wv; rowbase = 640 + cm * 64; }
  else              { src = Wo; rowbase = 960 + cm * 64; }
  const int c0 = cm * 64;
  const int k0 = kx * 64;
#pragma unroll
  for (int i = 0; i < 4; ++i) {         // read 64k x 64c fp32, transpose to LDS
    int kr = (t >> 4) + i * 16, cc = (t & 15) * 4;
    float4 w4 = *(const float4*)&src[(size_t)(k0 + kr) * DM + c0 + cc];
    lt[(cc + 0) * 72 + kr] = f2b(w4.x);
    lt[(cc + 1) * 72 + kr] = f2b(w4.y);
    lt[(cc + 2) * 72 + kr] = f2b(w4.z);
    lt[(cc + 3) * 72 + kr] = f2b(w4.w);
  }
  __syncthreads();
#pragma unroll
  for (int i = 0; i < 2; ++i) {         // scatter to frag-major (8-short chunks)
    int idx = t + i * 256, cl = idx >> 3, ch = idx & 7;
    int c = rowbase + cl, k = k0 + ch * 8;
    *(uint4*)&Wtf[fmi(c >> 4, 10, k, c)] = *(const uint4*)&lt[cl * 72 + ch * 8];
  }
}

// ---------------- kernel 2: fused QKV projection (all-frag-major) ----------------
// Q/K: D[c][m] via mfma(W,x) -> uint2 stores. V: D[m][c] via mfma(x,W).
__global__ __launch_bounds__(256, 4) void qkv_gemm(
    const unsigned short* __restrict__ xbf, const unsigned short* __restrict__ Wtf,
    unsigned short* __restrict__ Qf, unsigned short* __restrict__ Kf,
    unsigned short* __restrict__ Vf) {
  const int t = threadIdx.x;
  const int w = t >> 6, lane = t & 63, quad = lane >> 4, ln = lane & 15;
  const int m0 = blockIdx.x * 64;
  const int cy = blockIdx.y;                  // 0..14
  const int a = cy / 5;                       // 0=Q 1=K 2=V
  const int cc0 = (cy % 5) * 64;
  const int mt = (m0 >> 4) + w;
  const int ct0 = a * 20 + (cc0 >> 4);

  f32x4 acc[4] = {{0,0,0,0},{0,0,0,0},{0,0,0,0},{0,0,0,0}};
  for (int kc = 0; kc < 10; ++kc) {
    bf16x8 xf = ld_bf8(xbf + ((size_t)(mt * 10 + kc)) * 512 + lane * 8);
#pragma unroll
    for (int nt = 0; nt < 4; ++nt) {
      bf16x8 wf = ld_bf8(Wtf + ((size_t)((ct0 + nt) * 10 + kc)) * 512 + lane * 8);
      if (a < 2) acc[nt] = mfma16(wf, xf, acc[nt]);   // D[c=quad*4+r][m=ln]
      else       acc[nt] = mfma16(xf, wf, acc[nt]);   // D[m=quad*4+r][c=ln]
    }
  }
  if (a == 0) {
    const int m = m0 + w * 16 + ln;
#pragma unroll
    for (int nt = 0; nt < 4; ++nt) {
      int c = cc0 + nt * 16 + quad * 4;       // r=0 base; no h/8-boundary crossing
      int h = c / DH, d = c % DH;
      uint2 pk = pack4(acc[nt][0] * QSCALE, acc[nt][1] * QSCALE,
                       acc[nt][2] * QSCALE, acc[nt][3] * QSCALE);
      *(uint2*)&Qf[fmi(h * 256 + (m >> 4), 2, d, m)] = pk;
    }
  } else if (a == 1) {
    const int m = m0 + w * 16 + ln;
#pragma unroll
    for (int nt = 0; nt < 4; ++nt) {
      int c = cc0 + nt * 16 + quad * 4;
      int h = c / DH, d = c % DH;
      uint2 pk = pack4(acc[nt][0], acc[nt][1], acc[nt][2], acc[nt][3]);
      size_t base = ((size_t)h * 256 + (m >> 4)) * KFJB;
      size_t idx = (d < 32)
          ? base + (size_t)(d >> 3) * 128 + (size_t)(m & 15) * 8 + (d & 7)
          : base + 512 + (size_t)(m & 15) * 8 + (d - 32);
      *(uint2*)&Kf[idx] = pk;
    }
  } else {
    const int mb = m0 + w * 16 + quad * 4;    // r=0 base (4 consecutive m)
#pragma unroll
    for (int nt = 0; nt < 4; ++nt) {
      int c = cc0 + nt * 16 + ln;
      int h = c / DH, d = c % DH;
      uint2 pk = pack4(acc[nt][0], acc[nt][1], acc[nt][2], acc[nt][3]);
      size_t idx = ((((((size_t)(h * 64 + (mb >> 6)) * 3 + (d >> 4)) * 2 +
                       ((mb >> 5) & 1)) * 4 + ((mb >> 3) & 3)) * 16 + (d & 15))) * 8 +
                   (mb & 7);
      *(uint2*)&Vf[idx] = pk;
    }
  }
}

// ---------------- kernel 3: barrier-free masked attention (2-jt batch) ----------
// grid (32 q-tiles of 128 rows, 8 heads, KS=4); block 256 = 4 waves x 32 q-rows.
// Two jt iterations' QK+exp+pack run before one lgkmcnt wait; then two PV runs —
// doubles independent work across the LDS-round-trip + exp dependency chain.
__global__ __launch_bounds__(256, 4) void attn_kernel(
    const unsigned short* __restrict__ Qf, const unsigned short* __restrict__ Kf,
    const unsigned short* __restrict__ Vf, const unsigned char* __restrict__ sigb,
    unsigned short* __restrict__ Opf, float* __restrict__ Lpart) {
  __shared__ __align__(16) unsigned short pt[4][2][32 * PSTR];  // 34816 B
  const int t = threadIdx.x;
  const int w = t >> 6, lane = t & 63, quad = lane >> 4, ln = lane & 15;
  const int h = blockIdx.y, qt = blockIdx.x, sp = blockIdx.z;
  const int qrow = qt * 128 + w * 32;
  const int j0 = sp * 16;

  const unsigned short* Kfh = Kf + (size_t)h * 256 * KFJB;
  const unsigned short* Vfh = Vf + (size_t)h * 196608;   // 64jt * 3ot * 2c * 512
  const uint4 z4 = {0, 0, 0, 0};
  const uint4 ones4 = {0x3F803F80u, 0x3F803F80u, 0x3F803F80u, 0x3F803F80u};
  const bool vone = (ln == 8);             // d=40 rows of the ot=2 V-frag -> 1.0

  bf16x8 qa[2][2];
  unsigned sqx4[2], uqx4[2];
  f32x4 o[3][2] = {{{0,0,0,0},{0,0,0,0}},{{0,0,0,0},{0,0,0,0}},{{0,0,0,0},{0,0,0,0}}};

#pragma unroll
  for (int tq = 0; tq < 2; ++tq) {
    int row = qrow + tq * 16 + ln;
    size_t qbase = ((size_t)(h * 256 + qt * 8 + w * 2 + tq) * 2) * 512;
    qa[tq][0] = ld_bf8(Qf + qbase + lane * 8);          // k 0..31, contiguous 1KB
    uint4 q1 = z4;                                      // k 32..63: quad0 real
    if (quad == 0) q1 = *(const uint4*)(Qf + qbase + 512 + lane * 8);
    qa[tq][1] = __builtin_bit_cast(bf16x8, q1);
    unsigned s = sigb[row];
    sqx4[tq] = s * 0x01010101u;
    uqx4[tq] = (s == 0u) ? 0xFFFFFFFFu : 0u;
    if (s == 0u) {                 // uniform row: logits exactly 0 -> p = 1
      qa[tq][0] = __builtin_bit_cast(bf16x8, z4);
      qa[tq][1] = __builtin_bit_cast(bf16x8, z4);
    }
  }

  for (int jtp = j0; jtp < j0 + 16; jtp += 2) {
    uint4 vfr[2][6];
    // ---- stage A: QK + masked exp + pack for jtp and jtp+1
#pragma unroll
    for (int u = 0; u < 2; ++u) {
      const int jt = jtp + u;
      uint4 kfr0[4], kfr1[4];
#pragma unroll
      for (int nt = 0; nt < 4; ++nt) {
        const unsigned short* kb = Kfh + (size_t)(jt * 4 + nt) * KFJB;
        kfr0[nt] = *(const uint4*)(kb + lane * 8);
        kfr1[nt] = z4;
        if (lane < 16) kfr1[nt] = *(const uint4*)(kb + 512 + lane * 8);
      }
#pragma unroll
      for (int ot = 0; ot < 3; ++ot)
#pragma unroll
        for (int c = 0; c < 2; ++c)
          vfr[u][ot * 2 + c] = *(const uint4*)(Vfh +
              ((size_t)((jt * 3 + ot) * 2 + c)) * 512 + lane * 8);
      if (vone) { vfr[u][4] = ones4; vfr[u][5] = ones4; }

      unsigned short* ptu = &pt[w][u][0];
#pragma unroll
      for (int nt = 0; nt < 4; ++nt) {
        bf16x8 ka0 = __builtin_bit_cast(bf16x8, kfr0[nt]);
        bf16x8 ka1 = __builtin_bit_cast(bf16x8, kfr1[nt]);
        unsigned spj = *(const unsigned*)(sigb + jt * 64 + nt * 16 + quad * 4);
#pragma unroll
        for (int tq = 0; tq < 2; ++tq) {
          f32x4 acc = {0.f, 0.f, 0.f, 0.f};
          acc = mfma16(ka0, qa[tq][0], acc);    // S^T[j=nt*16+quad*4+r][m=ln]
          acc = mfma16(ka1, qa[tq][1], acc);
          unsigned m4 = (spj & sqx4[tq]) | uqx4[tq];   // byte r != 0 <=> unmasked
          unsigned uu[4];
#pragma unroll
          for (int r = 0; r < 4; ++r) {
            unsigned mb = (m4 >> (8 * r)) & 255u;      // v_bfe
            float am = mb ? acc[r] : -3.0e38f;         // masked -> exp2 = 0
            uu[r] = __builtin_bit_cast(unsigned, fexp2(am));
          }
          uint2 pk;                                     // truncate-to-bf16 pack
          pk.x = (uu[0] >> 16) | (uu[1] & 0xffff0000u); // (j+0, j+1)
          pk.y = (uu[2] >> 16) | (uu[3] & 0xffff0000u); // (j+2, j+3)
          *(uint2*)&ptu[(tq * 16 + ln) * PSTR + nt * 16 + quad * 4] = pk;  // b64
        }
      }
    }
    asm volatile("s_waitcnt lgkmcnt(0)" ::: "memory");   // wave-private P RAW
    // ---- stage B: PV for both jt
#pragma unroll
    for (int u = 0; u < 2; ++u) {
      unsigned short* ptu = &pt[w][u][0];
      bf16x8 pb[2][2];
#pragma unroll
      for (int tq = 0; tq < 2; ++tq) {
        pb[tq][0] = ld_bf8(&ptu[(tq * 16 + ln) * PSTR + quad * 8]);
        pb[tq][1] = ld_bf8(&ptu[(tq * 16 + ln) * PSTR + 32 + quad * 8]);
      }
#pragma unroll
      for (int ot = 0; ot < 3; ++ot) {
        bf16x8 va0 = __builtin_bit_cast(bf16x8, vfr[u][ot * 2]);
        bf16x8 va1 = __builtin_bit_cast(bf16x8, vfr[u][ot * 2 + 1]);
#pragma unroll
        for (int tq = 0; tq < 2; ++tq) {
          o[ot][tq] = mfma16(va0, pb[tq][0], o[ot][tq]);   // O^T[d][m]
          o[ot][tq] = mfma16(va1, pb[tq][1], o[ot][tq]);
        }
      }
    }
  }

  // epilogue: O^T d = ot*16+quad*4+r; write frag-major Opf; d=40 -> denominator
#pragma unroll
  for (int tq = 0; tq < 2; ++tq) {
    int m = qrow + tq * 16 + ln;
#pragma unroll
    for (int ot = 0; ot < 3; ++ot) {
      int d0 = ot * 16 + quad * 4;
      if (d0 < DH) {
        int c = h * DH + d0;                  // 4 consecutive c, no 8-crossing
        uint2 pk = pack4(o[ot][tq][0], o[ot][tq][1], o[ot][tq][2], o[ot][tq][3]);
        *(uint2*)&Opf[fmi(sp * 256 + (m >> 4), 10, c, m)] = pk;
      }
    }
    if (quad == 2)
      Lpart[sp * NT + m] = o[2][tq][0];       // MFMA-computed denominator
  }
}

// ---------------- kernel 4: out projection + split-K combine + bias ----------------
// D[c][m] via mfma(Wo, A): float4 out stores + float4 bias loads.
__global__ __launch_bounds__(256, 4) void out_gemm(
    const unsigned short* __restrict__ Opf, const float* __restrict__ Lpart,
    const unsigned short* __restrict__ Wtf, const float* __restrict__ bo,
    float* __restrict__ out) {
  const int t = threadIdx.x;
  const int w = t >> 6, lane = t & 63, quad = lane >> 4, ln = lane & 15;
  const int m0 = blockIdx.x * 64;
  const int cc0 = blockIdx.y * 64;
  const int mt = (m0 >> 4) + w;
  const int m = m0 + w * 16 + ln;
  const int ct0 = 60 + (cc0 >> 4);
  float ls = 0.f;
#pragma unroll
  for (int sp = 0; sp < KS; ++sp) ls += Lpart[sp * NT + m];
  const float inv = 1.f / ls;

  f32x4 acc[4] = {{0,0,0,0},{0,0,0,0},{0,0,0,0},{0,0,0,0}};
  for (int kc = 0; kc < 10; ++kc) {
    float s8[8] = {0, 0, 0, 0, 0, 0, 0, 0};
#pragma unroll
    for (int sp = 0; sp < KS; ++sp) {
      uint4 v = *(const uint4*)(Opf + ((size_t)((sp * 256 + mt) * 10 + kc)) * 512 +
                                lane * 8);
      unsigned vv[4] = {v.x, v.y, v.z, v.w};
#pragma unroll
      for (int j = 0; j < 4; ++j) {
        s8[2 * j]     += __builtin_bit_cast(float, vv[j] << 16);
        s8[2 * j + 1] += __builtin_bit_cast(float, vv[j] & 0xffff0000u);
      }
    }
    unsigned short af8[8];
#pragma unroll
    for (int j = 0; j < 8; ++j) af8[j] = f2b(s8[j] * inv);
    bf16x8 af = ld_bf8(af8);
#pragma unroll
    for (int nt = 0; nt < 4; ++nt) {
      bf16x8 wf = ld_bf8(Wtf + ((size_t)((ct0 + nt) * 10 + kc)) * 512 + lane * 8);
      acc[nt] = mfma16(wf, af, acc[nt]);      // D[c=quad*4+r][m=ln]
    }
  }
#pragma unroll
  for (int nt = 0; nt < 4; ++nt) {
    int c = cc0 + nt * 16 + quad * 4;
    float4 bv = *(const float4*)(bo + c);
    float4 ov;
    ov.x = acc[nt][0] + bv.x;
    ov.y = acc[nt][1] + bv.y;
    ov.z = acc[nt][2] + bv.z;
    ov.w = acc[nt][3] + bv.w;
    *(float4*)(out + (size_t)m * DM + c) = ov;
  }
}

// ---------------- launcher ----------------
extern "C" void kernel_launch(void* const* d_in, const int* in_sizes, int n_in,
                              void* d_out, int out_size, void* d_ws, size_t ws_size,
                              hipStream_t stream) {
  const float* x  = (const float*)d_in[0];
  const float* g  = (const float*)d_in[1];
  const float* Wq = (const float*)d_in[2];
  const float* Wk = (const float*)d_in[3];
  const float* Wv = (const float*)d_in[4];
  const float* Wo = (const float*)d_in[5];
  const float* bo = (const float*)d_in[6];
  float* out = (float*)d_out;

  char* ws = (char*)d_ws;
  const size_t SIG_OFF = 0;
  const size_t XBF_OFF = 16384;
  const size_t WTF_OFF = XBF_OFF + (size_t)NT * DM * 2;             // +2.62 MB
  const size_t QF_OFF  = WTF_OFF + (size_t)1280 * DM * 2;           // +0.82 MB
  const size_t KF_OFF  = QF_OFF + (size_t)NH * 256 * 2 * 512 * 2;   // +4.19 MB
  const size_t VF_OFF  = KF_OFF + (size_t)NH * 256 * KFJB * 2;      // +2.62 MB
  const size_t OPF_OFF = VF_OFF + (size_t)NH * 196608 * 2;          // +3.15 MB
  const size_t LP_OFF  = OPF_OFF + (size_t)KS * 256 * 10 * 512 * 2; // +10.49 MB
  unsigned char* sigb  = (unsigned char*)(ws + SIG_OFF);
  unsigned short* xbf  = (unsigned short*)(ws + XBF_OFF);
  unsigned short* Wtf  = (unsigned short*)(ws + WTF_OFF);
  unsigned short* Qf   = (unsigned short*)(ws + QF_OFF);
  unsigned short* Kf   = (unsigned short*)(ws + KF_OFF);
  unsigned short* Vf   = (unsigned short*)(ws + VF_OFF);
  unsigned short* Opf  = (unsigned short*)(ws + OPF_OFF);
  float* Lpart         = (float*)(ws + LP_OFF);

  // No memset: Qf half-1 quad>=1 garbage zeroed in-register; Vf d=40 ones
  // in-register; Vf d=41..47 garbage feeds only discarded lanes (no NaN).
  prep_kernel<<<244, 256, 0, stream>>>(x, g, Wq, Wk, Wv, Wo, xbf, sigb, Wtf);
  qkv_gemm<<<dim3(64, 15), 256, 0, stream>>>(xbf, Wtf, Qf, Kf, Vf);
  attn_kernel<<<dim3(32, NH, KS), 256, 0, stream>>>(Qf, Kf, Vf, sigb, Opf, Lpart);
  out_gemm<<<dim3(64, 5), 256, 0, stream>>>(Opf, Lpart, Wtf, bo, out);
}